// Round 7
// baseline (369.049 us; speedup 1.0000x reference)
//
#include <hip/hip_runtime.h>
#include <math.h>

// Problem constants
#define N_TOK 131072   // 32*64*64 tokens
#define D     64       // embedding dim
#define K     1024     // codebook size

// Output layout (floats, concatenated in reference return order):
#define OUT_LOSS  8388608
#define OUT_IDX   8388609
#define OUT_PERP  8519681

// ws layout (bytes):
//   0       counts   u32[1024]
//   4096    enorm    f32[1024]   np-exact ||e||^2 (pairwise sum)
//   8192    sinit    f32[1024]   fp64-accurate ||e||^2 (screen C-init)
//   12288   sse      f32
//   16384   w_hi     s16[65536]  bf16 hi split of w (128 KB)
//   147456  w_lo     s16[65536]  bf16 lo split of w (128 KB)

#define W_WINDOW 1e-4f

typedef short bf16x8 __attribute__((ext_vector_type(8)));
typedef float f32x4  __attribute__((ext_vector_type(4)));

// ---------------------------------------------------------------------------
// np pairwise-sum base case for n=64 (8 accumulators) — bit-exact vs numpy.
// ---------------------------------------------------------------------------
__device__ __forceinline__ float np_pairsum64(const float* sq) {
    float r[8];
#pragma unroll
    for (int j = 0; j < 8; ++j) r[j] = sq[j];
#pragma unroll
    for (int i = 8; i < 64; i += 8) {
#pragma unroll
        for (int j = 0; j < 8; ++j) r[j] = __fadd_rn(r[j], sq[i + j]);
    }
    return __fadd_rn(
        __fadd_rn(__fadd_rn(r[0], r[1]), __fadd_rn(r[2], r[3])),
        __fadd_rn(__fadd_rn(r[4], r[5]), __fadd_rn(r[6], r[7])));
}

__device__ __forceinline__ short bf16_trunc(float f) {
    return (short)(__float_as_uint(f) >> 16);
}
__device__ __forceinline__ float bf16_up(short s) {
    return __uint_as_float(((unsigned)(unsigned short)s) << 16);
}

// ---------------------------------------------------------------------------
// Prep: enorm (np-exact), sinit (fp64-accurate), bf16 splits of w, zero ws.
// ---------------------------------------------------------------------------
__global__ void vq_prep(const float* __restrict__ w,
                        float* __restrict__ enorm,
                        float* __restrict__ sinit,
                        short* __restrict__ w_hi,
                        short* __restrict__ w_lo,
                        unsigned* __restrict__ counts,
                        float* __restrict__ sse) {
    int k = blockIdx.x * blockDim.x + threadIdx.x;
    if (k < K) {
        const float* wr = w + (size_t)k * D;
        float sq[D];
        double acc = 0.0;
#pragma unroll
        for (int i = 0; i < D; ++i) {
            float v = wr[i];
            sq[i] = __fmul_rn(v, v);
            acc += (double)v * (double)v;
            short hi = bf16_trunc(v);
            float res = v - bf16_up(hi);
            short lo = bf16_trunc(res);
            w_hi[(size_t)k * D + i] = hi;
            w_lo[(size_t)k * D + i] = lo;
        }
        enorm[k] = np_pairsum64(sq);
        sinit[k] = (float)acc;
        counts[k] = 0u;
    }
    if (k == 0) *sse = 0.f;
}

// ---------------------------------------------------------------------------
// Screen kernel. Block = 256 threads = 4 waves = 128 tokens (wave -> 32
// tokens = 2 M-tiles). Single MFMA pass over 64 code tiles with top-2
// tracking; B staged in LDS (fragment order) via global_load_lds, 4-tile
// double-buffered phases; wave-parallel np-exact rescue for window tokens.
// ---------------------------------------------------------------------------
#define MFMA(A, B, C) __builtin_amdgcn_mfma_f32_16x16x32_bf16(A, B, C, 0, 0, 0)

__global__ __launch_bounds__(256, 4)
void vq_screen(const float* __restrict__ x,
               const float* __restrict__ w,
               const float* __restrict__ enorm,
               const float* __restrict__ sinit,
               const short* __restrict__ w_hi,
               const short* __restrict__ w_lo,
               float* __restrict__ out,
               unsigned* __restrict__ counts,
               float* __restrict__ sse) {
    const int lane = threadIdx.x & 63;
    const int wv   = __builtin_amdgcn_readfirstlane(threadIdx.x >> 6);  // 0..3
    const int quad = lane >> 4;          // 0..3
    const int col  = lane & 15;

    const int tokBlock = blockIdx.x * 128;
    const int tokWave  = tokBlock + wv * 32;

    // LDS: B double-buffer [buf][tileInPhase][chunk][512 shorts=1KB/chunk]
    // chunk: 0=hi ks0, 1=hi ks1, 2=lo ks0, 3=lo ks1; frag order (lane*16B).
    __shared__ short sB[2][4][4][512];
    __shared__ float sSinit[K];
    __shared__ float sd1[128];
    __shared__ float sd2[128];
    __shared__ int   si1[128];
    __shared__ int   rescueList[128];
    __shared__ unsigned rescueCnt;

    if (threadIdx.x == 0) rescueCnt = 0u;
    ((float4*)sSinit)[threadIdx.x] = ((const float4*)sinit)[threadIdx.x];

    // --- A fragments: bf16 hi/lo splits of (-2 * x) ---------------------
    bf16x8 Ah[2][2], Al[2][2];
#pragma unroll
    for (int mt = 0; mt < 2; ++mt) {
#pragma unroll
        for (int ks = 0; ks < 2; ++ks) {
            const float4* ap = (const float4*)(x + (size_t)(tokWave + mt * 16 + col) * D
                                               + ks * 32 + quad * 8);
            float4 u0 = ap[0], u1 = ap[1];
            float f[8] = {u0.x, u0.y, u0.z, u0.w, u1.x, u1.y, u1.z, u1.w};
            bf16x8 h, l;
#pragma unroll
            for (int j = 0; j < 8; ++j) {
                float v = -2.0f * f[j];
                short hi = bf16_trunc(v);
                float res = v - bf16_up(hi);
                h[j] = hi;
                l[j] = bf16_trunc(res);
            }
            Ah[mt][ks] = h;
            Al[mt][ks] = l;
        }
    }

    // Staging: wave wv owns chunk wv (arr = hi/lo, ks = wv&1).
    const short* sArr  = (wv < 2) ? w_hi : w_lo;
    const int    sKs   = wv & 1;
    const int    srcOff = col * D + sKs * 32 + quad * 8;  // shorts within tile

#define STAGE(ph, b)                                                          \
    {                                                                         \
        _Pragma("unroll")                                                     \
        for (int tt_ = 0; tt_ < 4; ++tt_) {                                   \
            const short* srcp_ = sArr + (size_t)((ph) * 4 + tt_) * 16 * D + srcOff; \
            __builtin_amdgcn_global_load_lds(                                 \
                (const __attribute__((address_space(1))) void*)srcp_,         \
                (__attribute__((address_space(3))) void*)&sB[b][tt_][wv][0],  \
                16, 0, 0);                                                    \
        }                                                                     \
    }

    STAGE(0, 0)
    __syncthreads();  // buf0 + sSinit ready (vmcnt drain before barrier)

    // Top-2 state: slots 0..3 = C0 rows, 4..7 = C1 rows.
    float m1[8], m2[8];
    int   i1[8];
#pragma unroll
    for (int s = 0; s < 8; ++s) { m1[s] = INFINITY; m2[s] = INFINITY; i1[s] = 0; }

    for (int ph = 0; ph < 16; ++ph) {
        const int b = ph & 1;
        if (ph < 15) STAGE(ph + 1, b ^ 1)
#pragma unroll
        for (int tt = 0; tt < 4; ++tt) {
            const int cbase = ph * 64 + tt * 16;
            bf16x8 Bh0 = *(const bf16x8*)&sB[b][tt][0][lane * 8];
            bf16x8 Bh1 = *(const bf16x8*)&sB[b][tt][1][lane * 8];
            bf16x8 Bl0 = *(const bf16x8*)&sB[b][tt][2][lane * 8];
            bf16x8 Bl1 = *(const bf16x8*)&sB[b][tt][3][lane * 8];
            float si = sSinit[cbase + col];
            f32x4 C0 = {si, si, si, si};
            f32x4 C1 = {si, si, si, si};
            C0 = MFMA(Ah[0][0], Bh0, C0); C0 = MFMA(Ah[0][1], Bh1, C0);
            C0 = MFMA(Ah[0][0], Bl0, C0); C0 = MFMA(Ah[0][1], Bl1, C0);
            C0 = MFMA(Al[0][0], Bh0, C0); C0 = MFMA(Al[0][1], Bh1, C0);
            C1 = MFMA(Ah[1][0], Bh0, C1); C1 = MFMA(Ah[1][1], Bh1, C1);
            C1 = MFMA(Ah[1][0], Bl0, C1); C1 = MFMA(Ah[1][1], Bl1, C1);
            C1 = MFMA(Al[1][0], Bh0, C1); C1 = MFMA(Al[1][1], Bh1, C1);
            const int code = cbase + col;
#pragma unroll
            for (int r = 0; r < 4; ++r) {
                {   // slot r (M-tile 0)
                    float c = C0[r];
                    m2[r] = fminf(m2[r], fmaxf(m1[r], c));  // median update
                    bool lt = c < m1[r];
                    i1[r] = lt ? code : i1[r];
                    m1[r] = fminf(m1[r], c);
                }
                {   // slot 4+r (M-tile 1)
                    float c = C1[r];
                    m2[4 + r] = fminf(m2[4 + r], fmaxf(m1[4 + r], c));
                    bool lt = c < m1[4 + r];
                    i1[4 + r] = lt ? code : i1[4 + r];
                    m1[4 + r] = fminf(m1[4 + r], c);
                }
            }
        }
        __syncthreads();
    }

    // Cross-lane top-2 merge over the 16 cols of each quad.
#pragma unroll
    for (int s = 0; s < 8; ++s) {
#pragma unroll
        for (int msk = 1; msk <= 8; msk <<= 1) {
            float om1 = __shfl_xor(m1[s], msk, 64);
            int   oi1 = __shfl_xor(i1[s], msk, 64);
            float om2 = __shfl_xor(m2[s], msk, 64);
            float nm2 = fminf(fmaxf(m1[s], om1), fminf(m2[s], om2));
            bool  take = om1 < m1[s];
            m1[s] = take ? om1 : m1[s];
            i1[s] = take ? oi1 : i1[s];
            m2[s] = nm2;
        }
    }

    // Publish per-token results (lane col==0 of each quad holds valid data).
    if (col == 0) {
#pragma unroll
        for (int s = 0; s < 8; ++s) {
            int tl = wv * 32 + (s >> 2) * 16 + quad * 4 + (s & 3);
            sd1[tl] = m1[s];
            sd2[tl] = m2[s];
            si1[tl] = i1[s];
        }
    }
    __syncthreads();

    // --- Epilogue part 1: direct winners; enqueue rescue tokens ---------
    if (threadIdx.x < 128) {
        const int tl = threadIdx.x;
        const int t  = tokBlock + tl;
        float bm1 = sd1[tl], bm2 = sd2[tl];
        int   win = si1[tl];
        bool  resc = (bm2 <= bm1 + W_WINDOW);
        float err = 0.f;
        if (resc) {
            unsigned u = atomicAdd(&rescueCnt, 1u);
            rescueList[u] = tl;
        } else {
            const float4* qr  = (const float4*)(w + (size_t)win * D);
            const float4* xp2 = (const float4*)(x + (size_t)t * D);
            float4*       oq  = (float4*)(out + (size_t)t * D);
#pragma unroll
            for (int i = 0; i < 16; ++i) {
                float4 q = qr[i];
                float4 xv = xp2[i];
                float e0 = q.x - xv.x, e1 = q.y - xv.y;
                float e2 = q.z - xv.z, e3 = q.w - xv.w;
                err = fmaf(e0, e0, err);
                err = fmaf(e1, e1, err);
                err = fmaf(e2, e2, err);
                err = fmaf(e3, e3, err);
                oq[i] = q;
            }
            out[OUT_IDX + t] = (float)win;
            atomicAdd(&counts[win], 1u);
        }
#pragma unroll
        for (int o = 32; o > 0; o >>= 1) err += __shfl_down(err, o, 64);
        if (lane == 0) atomicAdd(sse, err);
    }
    __syncthreads();

    // --- Rescue: one wave per token, np-exact full 1024-code scan -------
    const unsigned nr = rescueCnt;
    for (unsigned u = wv; u < nr; u += 4) {
        const int tl = rescueList[u];
        const int t  = tokBlock + tl;

        // All lanes load the token row (wave-uniform address -> broadcast).
        const float4* xp = (const float4*)(x + (size_t)t * D);
        float4 v[16];
#pragma unroll
        for (int i = 0; i < 16; ++i) v[i] = xp[i];

        // Sx np-exact (8 accumulators, ascending order).
        float r0, r1, r2, r3, r4, r5, r6, r7;
        r0 = __fmul_rn(v[0].x, v[0].x); r1 = __fmul_rn(v[0].y, v[0].y);
        r2 = __fmul_rn(v[0].z, v[0].z); r3 = __fmul_rn(v[0].w, v[0].w);
        r4 = __fmul_rn(v[1].x, v[1].x); r5 = __fmul_rn(v[1].y, v[1].y);
        r6 = __fmul_rn(v[1].z, v[1].z); r7 = __fmul_rn(v[1].w, v[1].w);
#pragma unroll
        for (int i = 2; i < 16; i += 2) {
            r0 = __fadd_rn(r0, __fmul_rn(v[i].x, v[i].x));
            r1 = __fadd_rn(r1, __fmul_rn(v[i].y, v[i].y));
            r2 = __fadd_rn(r2, __fmul_rn(v[i].z, v[i].z));
            r3 = __fadd_rn(r3, __fmul_rn(v[i].w, v[i].w));
            r4 = __fadd_rn(r4, __fmul_rn(v[i + 1].x, v[i + 1].x));
            r5 = __fadd_rn(r5, __fmul_rn(v[i + 1].y, v[i + 1].y));
            r6 = __fadd_rn(r6, __fmul_rn(v[i + 1].z, v[i + 1].z));
            r7 = __fadd_rn(r7, __fmul_rn(v[i + 1].w, v[i + 1].w));
        }
        float Sx = __fadd_rn(
            __fadd_rn(__fadd_rn(r0, r1), __fadd_rn(r2, r3)),
            __fadd_rn(__fadd_rn(r4, r5), __fadd_rn(r6, r7)));

        // Lane handles codes c = j*64 + lane, j ascending (c ascending).
        float bestd = INFINITY;
        int   bestc = 0x7fffffff;
        for (int j = 0; j < 16; ++j) {
            int c = j * 64 + lane;
            const float4* wr4 = (const float4*)(w + (size_t)c * D);
            float a = 0.f;
#pragma unroll
            for (int i = 0; i < 16; ++i) {
                float4 q = wr4[i];
                a = __fmaf_rn(q.x, v[i].x, a);
                a = __fmaf_rn(q.y, v[i].y, a);
                a = __fmaf_rn(q.z, v[i].z, a);
                a = __fmaf_rn(q.w, v[i].w, a);
            }
            float dist = __fsub_rn(__fadd_rn(Sx, enorm[c]), __fmul_rn(2.0f, a));
            if (dist < bestd || (dist == bestd && c < bestc)) {
                bestd = dist; bestc = c;
            }
        }
        // Lexicographic (dist, index) cross-lane reduce.
#pragma unroll
        for (int msk = 1; msk <= 32; msk <<= 1) {
            float od = __shfl_xor(bestd, msk, 64);
            int   oc = __shfl_xor(bestc, msk, 64);
            bool take = (od < bestd) || (od == bestd && oc < bestc);
            bestd = take ? od : bestd;
            bestc = take ? oc : bestc;
        }

        // Epilogue for this token: lane l handles element l.
        float qv = w[(size_t)bestc * D + lane];
        float xv = x[(size_t)t * D + lane];
        float e  = qv - xv;
        float err = e * e;
        out[(size_t)t * D + lane] = qv;
#pragma unroll
        for (int o = 32; o > 0; o >>= 1) err += __shfl_down(err, o, 64);
        if (lane == 0) {
            atomicAdd(sse, err);
            out[OUT_IDX + t] = (float)bestc;
            atomicAdd(&counts[bestc], 1u);
        }
    }
}
#undef STAGE
#undef MFMA

// ---------------------------------------------------------------------------
// Finalize: vq_loss and perplexity.
// ---------------------------------------------------------------------------
__global__ void vq_fin(const unsigned* __restrict__ counts,
                       const float* __restrict__ sse,
                       float* __restrict__ out) {
    __shared__ float red[256];
    float s = 0.f;
    for (int k = threadIdx.x; k < K; k += 256) {
        float p = (float)counts[k] * (1.0f / (float)N_TOK);
        s += p * logf(p + 1e-10f);
    }
    red[threadIdx.x] = s;
    __syncthreads();
    for (int st = 128; st > 0; st >>= 1) {
        if (threadIdx.x < st) red[threadIdx.x] += red[threadIdx.x + st];
        __syncthreads();
    }
    if (threadIdx.x == 0) {
        out[OUT_PERP] = expf(-red[0]);
        out[OUT_LOSS] = 1.25f * (*sse) * (1.0f / 8388608.0f);  // (1+0.25)*MSE
    }
}

// ---------------------------------------------------------------------------
extern "C" void kernel_launch(void* const* d_in, const int* in_sizes, int n_in,
                              void* d_out, int out_size, void* d_ws, size_t ws_size,
                              hipStream_t stream) {
    const float* x = (const float*)d_in[0];  // [32,64,64,64] fp32
    const float* w = (const float*)d_in[1];  // [1024,64] fp32
    float* out = (float*)d_out;

    char* ws = (char*)d_ws;
    unsigned* counts = (unsigned*)(ws + 0);
    float*    enorm  = (float*)(ws + 4096);
    float*    sinit  = (float*)(ws + 8192);
    float*    sse    = (float*)(ws + 12288);
    short*    w_hi   = (short*)(ws + 16384);
    short*    w_lo   = (short*)(ws + 147456);

    vq_prep<<<4, 256, 0, stream>>>(w, enorm, sinit, w_hi, w_lo, counts, sse);
    vq_screen<<<N_TOK / 128, 256, 0, stream>>>(x, w, enorm, sinit, w_hi, w_lo,
                                               out, counts, sse);
    vq_fin<<<1, 256, 0, stream>>>(counts, sse, out);
}